// Round 24
// baseline (153.110 us; speedup 1.0000x reference)
//
#include <hip/hip_runtime.h>
#include <hip/hip_bf16.h>

// ABLATION ROUND: 4 co-compiled variants of the R20 kernel, launched
// back-to-back; per-dispatch dur_us in rocprof isolates the marginals.
//   MODE 3: prologue + MFMA-only loop (frags pre-read once; acc sunk by asm)
//   MODE 2: + in-loop ds_read fragment reads (stale slots, no staging)
//   MODE 1: + staging & counted waits (full K-loop), no epilogue
//   MODE 0: full kernel (only writer of out; launched LAST)
// Rule #17: non-0 modes keep acc live via asm volatile "v" sinks.
// Base: int8 implicit GEMM, wave-private 2-slot B ring, transposed-D.

typedef __attribute__((ext_vector_type(4))) int   i32x4;
typedef __attribute__((ext_vector_type(4))) float f32x4;

#define WTI8_BYTES (18 * 16384)
#define XPI8_BYTES (32 * 58 * 8192)

__device__ __forceinline__ void gload_lds16(const void* g, void* l) {
    __builtin_amdgcn_global_load_lds(
        (const __attribute__((address_space(1))) void*)g,
        (__attribute__((address_space(3))) void*)l, 16, 0, 0);
}

// ---- weight prep: w[cout][cin][3][3] - 128 -> per-(s,wn) 4KB panels ----
__global__ void wprep_kernel(const float* __restrict__ w, char* __restrict__ wt) {
    int cidx = blockIdx.x * 256 + threadIdx.x;
    int byte0 = cidx * 16;
    int s    = byte0 >> 14;
    int wn   = (byte0 >> 12) & 3;
    int e4   = byte0 & 4095;
    int nn   = e4 >> 6;
    int koff = e4 & 63;
    int kl   = koff ^ ((nn & 3) << 4);
    int n = wn * 64 + nn;
    int r = s >> 1, ch = s & 1;
    union { char c[16]; i32x4 v; } u;
#pragma unroll
    for (int j = 0; j < 16; ++j) {
        int cin = ch * 64 + kl + j;
        u.c[j] = (char)((int)w[(size_t)n * 1152 + cin * 9 + r] - 128);
    }
    *(i32x4*)(wt + byte0) = u.v;
}

// ---- x prep: coalesced NCHW read -> swizzled padded NHWC int8 + colsum ----
__global__ void xprep_kernel(const float* __restrict__ x, const float* __restrict__ xzp,
                             char* __restrict__ xpi8, int* __restrict__ colsum) {
    int bhh = blockIdx.x;
    int b = bhh / 58, hh = bhh % 58;
    int tid = threadIdx.x;
    char* blob = xpi8 + (size_t)bhh * 8192;
    int w  = tid & 63;
    int cq = tid >> 6;
    __shared__ int ps[4][64];
    if (hh == 0 || hh == 57) {
        i32x4 z = {0, 0, 0, 0};
        *(i32x4*)(blob + tid * 32)      = z;
        *(i32x4*)(blob + tid * 32 + 16) = z;
        if (cq == 0) colsum[bhh * 64 + w] = 0;
        return;
    }
    const int ZX = (int)rintf(*xzp);
    bool valid = (w >= 1 && w <= 56);
    const float* xb = x + (size_t)b * 128 * 3136 + (size_t)(hh - 1) * 56 +
                      (valid ? (w - 1) : 0);
    int csum = 0;
#pragma unroll
    for (int u = 0; u < 2; ++u) {
        union { char c[16]; i32x4 v; } uu;
#pragma unroll
        for (int j = 0; j < 16; ++j) {
            int c = cq * 32 + u * 16 + j;
            int val = valid ? ((int)xb[(size_t)c * 3136] - ZX) : 0;
            uu.c[j] = (char)val;
            csum += val;
        }
        *(i32x4*)(blob + w * 128 + ((cq * 32 + u * 16) ^ ((w & 7) << 4))) = uu.v;
    }
    ps[cq][w] = csum;
    __syncthreads();
    if (cq == 0)
        colsum[bhh * 64 + w] = ps[0][w] + ps[1][w] + ps[2][w] + ps[3][w];
}

// ---- conv variants ----
template <int MODE>
__global__ __launch_bounds__(256, 2)
void conv_kernel(const char* __restrict__ wt,
                 const char* __restrict__ xpi8,
                 const int* __restrict__ colsum,
                 const float* __restrict__ bias,
                 const float* __restrict__ Mp,
                 const float* __restrict__ wzp,
                 const float* __restrict__ yzp,
                 float* __restrict__ out) {
    __shared__ __align__(1024) char As[32768];
    __shared__ __align__(1024) char Bp[32768];
    __shared__ int s2row[2][64];

    const int tid = threadIdx.x;
    const int lane = tid & 63;
    const int wn = tid >> 6;
    const int l15 = lane & 15, lg = lane >> 4;
    const int bx = blockIdx.x;
    const int b = bx / 28;
    const int h0 = (bx % 28) * 2;

    char* bpriv = Bp + wn * 8192;
    const char* bwsrc = wt + wn * 4096 + lane * 16;
    const int bfoff = (lg * 16) ^ ((l15 & 3) << 4);

    const char* agbase = xpi8 + (size_t)(b * 58 + h0) * 8192;
#pragma unroll
    for (int i = 0; i < 8; ++i)
        gload_lds16(agbase + i * 4096 + tid * 16, As + i * 4096 + tid * 16);
#pragma unroll
    for (int st = 0; st < 2; ++st)
#pragma unroll
        for (int i = 0; i < 4; ++i)
            gload_lds16(bwsrc + (size_t)st * 16384 + i * 1024,
                        bpriv + st * 4096 + i * 1024 + lane * 16);
    if (tid < 128) {
        int row = tid >> 6, m = tid & 63;
        int s = 0;
        if (m < 56) {
#pragma unroll
            for (int kh = 0; kh < 3; ++kh)
#pragma unroll
                for (int kw = 0; kw < 3; ++kw)
                    s += colsum[(b * 58 + h0 + row + kh) * 64 + m + kw];
        }
        s2row[row][m] = s;
    }

    i32x4 acc[4][8];
#pragma unroll
    for (int i = 0; i < 4; ++i)
#pragma unroll
        for (int j = 0; j < 8; ++j)
            acc[i][j] = (i32x4){0, 0, 0, 0};

    __syncthreads();

    if constexpr (MODE == 3) {
        // MFMA-only: frags read once (slot 0 valid post-barrier); the acc
        // dependency chain forces all 18x32 MFMAs to execute.
        i32x4 bfr[4], afr[8];
#pragma unroll
        for (int fn = 0; fn < 4; ++fn)
            bfr[fn] = *(const i32x4*)(bpriv + (fn * 16 + l15) * 64 + bfoff);
#pragma unroll
        for (int fm = 0; fm < 8; ++fm) {
            int wv = (fm & 3) * 16 + l15;
            int ab = (fm >> 2) * 8192 + wv * 128 +
                     ((lg * 16) ^ ((wv & 7) << 4));
            afr[fm] = *(const i32x4*)(As + ab);
        }
#pragma unroll
        for (int s = 0; s < 18; ++s)
#pragma unroll
            for (int fn = 0; fn < 4; ++fn)
#pragma unroll
                for (int fm = 0; fm < 8; ++fm)
                    acc[fn][fm] = __builtin_amdgcn_mfma_i32_16x16x64_i8(
                        bfr[fn], afr[fm], acc[fn][fm], 0, 0, 0);
    } else {
#pragma unroll
        for (int s = 0; s < 18; ++s) {
            const int kh = (s >> 1) / 3, kw = (s >> 1) % 3, ch = s & 1;
            const char* bslot = bpriv + (s & 1) * 4096;
            i32x4 bfr[4];
#pragma unroll
            for (int fn = 0; fn < 4; ++fn)
                bfr[fn] = *(const i32x4*)(bslot + (fn * 16 + l15) * 64 + bfoff);
            i32x4 afr[8];
#pragma unroll
            for (int fm = 0; fm < 8; ++fm) {
                int wv = (fm & 3) * 16 + l15 + kw;
                int wc = wv > 63 ? 63 : wv;
                int ab = ((fm >> 2) + kh) * 8192 + wc * 128 +
                         ((ch * 64 + lg * 16) ^ ((wc & 7) << 4));
                afr[fm] = *(const i32x4*)(As + ab);
            }
            if constexpr (MODE <= 1) {
                if (s < 16) {
                    asm volatile("s_waitcnt lgkmcnt(0)" ::: "memory");
#pragma unroll
                    for (int i = 0; i < 4; ++i)
                        gload_lds16(bwsrc + (size_t)(s + 2) * 16384 + i * 1024,
                                    bpriv + (s & 1) * 4096 + i * 1024 + lane * 16);
                    asm volatile("s_waitcnt vmcnt(4)" ::: "memory");
                } else if (s == 16) {
                    asm volatile("s_waitcnt vmcnt(0)" ::: "memory");
                }
            }
#pragma unroll
            for (int fn = 0; fn < 4; ++fn)
#pragma unroll
                for (int fm = 0; fm < 8; ++fm)
                    acc[fn][fm] = __builtin_amdgcn_mfma_i32_16x16x64_i8(
                        bfr[fn], afr[fm], acc[fn][fm], 0, 0, 0);
        }
    }

    if constexpr (MODE == 0) {
        const float Mv  = *Mp;
        const float yzv = *yzp;
        const float CWf = 128.0f - *wzp;
#pragma unroll
        for (int fn = 0; fn < 4; ++fn) {
#pragma unroll
            for (int reg = 0; reg < 4; ++reg) {
                const int cout = wn * 64 + fn * 16 + lg * 4 + reg;
                const float bv = bias[cout];
#pragma unroll
                for (int fm = 0; fm < 8; ++fm) {
                    const int row = fm >> 2;
                    const int m = (fm & 3) * 16 + l15;
                    if (m < 56) {
                        const size_t rowb =
                            ((size_t)(b * 256 + cout) * 56 + h0 + row) * 56;
                        float af = (float)acc[fn][fm][reg] +
                                   CWf * (float)s2row[row][m];
                        float v = (af + bv) * Mv + yzv;
                        v = fmaxf(v, yzv);
                        out[rowb + m] = rintf(v);
                    }
                }
            }
        }
    } else {
        // keep acc (and thus all MFMAs) live without storing (rule #17)
#pragma unroll
        for (int fn = 0; fn < 4; ++fn)
#pragma unroll
            for (int fm = 0; fm < 8; ++fm)
#pragma unroll
                for (int reg = 0; reg < 4; ++reg)
                    asm volatile("" :: "v"(acc[fn][fm][reg]));
    }
}

extern "C" void kernel_launch(void* const* d_in, const int* in_sizes, int n_in,
                              void* d_out, int out_size, void* d_ws, size_t ws_size,
                              hipStream_t stream) {
    const float* x    = (const float*)d_in[0];
    const float* w    = (const float*)d_in[1];
    const float* bias = (const float*)d_in[2];
    const float* Mp   = (const float*)d_in[3];
    const float* xzp  = (const float*)d_in[4];
    const float* wzp  = (const float*)d_in[5];
    const float* yzp  = (const float*)d_in[6];
    float* out = (float*)d_out;

    char* wt     = (char*)d_ws;
    char* xpi8   = wt + WTI8_BYTES;
    int*  colsum = (int*)(xpi8 + XPI8_BYTES);

    wprep_kernel<<<72, 256, 0, stream>>>(w, wt);
    xprep_kernel<<<32 * 58, 256, 0, stream>>>(x, xzp, xpi8, colsum);
    // ablation dispatches (no output writes), then the real kernel
    conv_kernel<3><<<32 * 28, 256, 0, stream>>>(wt, xpi8, colsum, bias, Mp, wzp, yzp, out);
    conv_kernel<2><<<32 * 28, 256, 0, stream>>>(wt, xpi8, colsum, bias, Mp, wzp, yzp, out);
    conv_kernel<1><<<32 * 28, 256, 0, stream>>>(wt, xpi8, colsum, bias, Mp, wzp, yzp, out);
    conv_kernel<0><<<32 * 28, 256, 0, stream>>>(wt, xpi8, colsum, bias, Mp, wzp, yzp, out);
}